// Round 1
// baseline (172.158 us; speedup 1.0000x reference)
//
#include <hip/hip_runtime.h>
#include <hip/hip_bf16.h>

typedef __bf16 bf16x8 __attribute__((ext_vector_type(8)));
typedef __bf16 bf16x4 __attribute__((ext_vector_type(4)));
typedef short  s16x4  __attribute__((ext_vector_type(4)));
typedef float  f32x4  __attribute__((ext_vector_type(4)));

#define MFMA32(a, b, c) __builtin_amdgcn_mfma_f32_16x16x32_bf16((a), (b), (c), 0, 0, 0)
#define MFMA16K(a, b, c) __builtin_amdgcn_mfma_f32_16x16x16bf16_1k((a), (b), (c), 0, 0, 0)

#if __has_builtin(__builtin_amdgcn_exp2f)
#define EXP2F(x) __builtin_amdgcn_exp2f(x)
#else
#define EXP2F(x) __expf(0.6931471805599453f * (x))
#endif

#define SPLIT 4
// BS=4, C=128, L=4096, D=64. Q pre-scaled by 0.125*log2(e): softmax in base 2.
// Fixed-bound softmax: p = 2^(s - BBOUND); the 2^(m-B) factor cancels in the
// final normalization. BBOUND folded into QK MFMA accumulator init.
#define QSCALE 0.18033688011112042f
#define BBOUND 12.0f

// K workspace layout (MFMA-permuted, per 64-key tile contiguous 8 KB):
//   Kp[b][kt][nt][half][quad][l15][i]   (key = nt*16+l15, d = half*32+quad*8+i)
// -> attn's A-fragment load for subtile nt is base + nt*1024 + half*512 +
//    lane*8: one fully-coalesced 1KB instruction.
// V workspace layout (permuted, per 64-key tile contiguous 8 KB):
//   Vp[b][kt][d][quad][kc][i]  (quad=key>>2&3, kc=key>>4, i=key&3)
// so attn lane (d, quad) reads its 16 V elements for all 4 kc-blocks as two
// contiguous b128 chunks (chunk index 2*quad+kc8, kc8 = kc>>1) straight from
// global (the 8 KB tile is L1-resident across the 4 waves' 8 reads).

// ---------------------------------------------------------------------------
// Kernel 1: QKV projection, bf16 MFMA. grid = 1024 (b x 256 tiles of 16 tok).
// Q bf16 [b][l][64] (LDS bounce -> coalesced 16B stores); K in permuted tile
// layout (LDS bounce -> 16B stores in 64B segments); V permuted (8B stores).
// ---------------------------------------------------------------------------
__global__ __launch_bounds__(256) void qkv_kernel(
    const float* __restrict__ inpt,
    const float* __restrict__ Wq, const float* __restrict__ bq,
    const float* __restrict__ Wk, const float* __restrict__ bk,
    const float* __restrict__ Wv, const float* __restrict__ bv,
    __bf16* __restrict__ Qws, __bf16* __restrict__ Kws, __bf16* __restrict__ VTws)
{
    __shared__ __align__(16) __bf16 xT[16 * 140];   // [tok][c]
    __shared__ __align__(16) __bf16 os[16 * 144];   // [tok][qk-out 0..127]
    const int bid = blockIdx.x;
    const int b   = bid >> 8;
    const int l0  = (bid & 255) << 4;               // 16 tokens
    const int t   = threadIdx.x;

    // stage x^T: thread (c = t>>1, half = t&1) loads 8 floats of row c
    {
        const int c = t >> 1, half = t & 1;
        const float* xin = inpt + ((size_t)(b * 128 + c)) * 4096 + l0 + half * 8;
        float4 v0 = *(const float4*)xin;
        float4 v1 = *(const float4*)(xin + 4);
        const int tok0 = half * 8;
        xT[(tok0 + 0) * 140 + c] = (__bf16)v0.x;
        xT[(tok0 + 1) * 140 + c] = (__bf16)v0.y;
        xT[(tok0 + 2) * 140 + c] = (__bf16)v0.z;
        xT[(tok0 + 3) * 140 + c] = (__bf16)v0.w;
        xT[(tok0 + 4) * 140 + c] = (__bf16)v1.x;
        xT[(tok0 + 5) * 140 + c] = (__bf16)v1.y;
        xT[(tok0 + 6) * 140 + c] = (__bf16)v1.z;
        xT[(tok0 + 7) * 140 + c] = (__bf16)v1.w;
    }
    __syncthreads();

    const int w    = t >> 6;
    const int lane = t & 63;
    const int quad = lane >> 4;
    const int l15  = lane & 15;

    f32x4 acc[3];
    #pragma unroll
    for (int j = 0; j < 3; ++j)
        #pragma unroll
        for (int r = 0; r < 4; ++r) acc[j][r] = 0.f;

    #pragma unroll
    for (int ks = 0; ks < 4; ++ks) {
        bf16x8 af = *(const bf16x8*)&xT[l15 * 140 + ks * 32 + quad * 8];
        #pragma unroll
        for (int j = 0; j < 3; ++j) {
            const int wn   = w * 3 + j;                 // n-tile 0..11
            const int msel = wn >> 2;                   // 0=Q 1=K 2=V
            const float* W = (msel == 0) ? Wq : ((msel == 1) ? Wk : Wv);
            const float* Wp = W + ((wn & 3) * 16 + l15) * 128 + ks * 32 + quad * 8;
            float4 wa = *(const float4*)Wp;
            float4 wb = *(const float4*)(Wp + 4);
            bf16x8 bf;
            bf[0] = (__bf16)wa.x; bf[1] = (__bf16)wa.y;
            bf[2] = (__bf16)wa.z; bf[3] = (__bf16)wa.w;
            bf[4] = (__bf16)wb.x; bf[5] = (__bf16)wb.y;
            bf[6] = (__bf16)wb.z; bf[7] = (__bf16)wb.w;
            acc[j] = MFMA32(af, bf, acc[j]);            // D[m=tok][n=out]
        }
    }

    // epilogue: D rows (quad*4+r) = token, col l15 = output within n-tile
    #pragma unroll
    for (int j = 0; j < 3; ++j) {
        const int wn   = w * 3 + j;
        const int msel = wn >> 2;
        const int o0   = (wn & 3) * 16;
        const float* bb = (msel == 0) ? bq : ((msel == 1) ? bk : bv);
        float bias = bb[o0 + l15];
        if (msel < 2) {
            // Q at cols [0,64), K at cols [64,128) of os
            const float scl = (msel == 0) ? QSCALE : 1.0f;
            const int oc = wn * 16 + l15;               // 0..127
            #pragma unroll
            for (int r = 0; r < 4; ++r)
                os[(quad * 4 + r) * 144 + oc] = (__bf16)((acc[j][r] + bias) * scl);
        } else {
            // permuted V store: token l0+quad*4+r -> tile kt, kc fixed per
            // block, quad_v == quad, i == r.
            const int d  = o0 + l15;
            const int kt = l0 >> 6;
            const int kc = (l0 >> 4) & 3;
            bf16x4 v;
            #pragma unroll
            for (int r = 0; r < 4; ++r) v[r] = (__bf16)(acc[j][r] + bias);
            *(bf16x4*)(VTws + (size_t)b * 262144 + kt * 4096
                       + d * 64 + quad * 16 + kc * 4) = v;
        }
    }
    __syncthreads();

    // Q store coalesced [l][64]; K store to the MFMA-permuted tile layout.
    // thread t -> token tok = t>>4, 16B chunk c = t&15.
    {
        const int tok = t >> 4, c = t & 15;
        bf16x8 v = *(const bf16x8*)&os[tok * 144 + c * 8];
        if (c < 8) {
            *(bf16x8*)(Qws + ((size_t)(b * 4096 + l0 + tok)) * 64 + c * 8) = v;
        } else {
            const int d8 = c - 8;                       // d = d8*8 .. +7
            __bf16* dst = Kws + (size_t)b * 262144
                + (l0 >> 6) * 4096            // tile
                + ((l0 >> 4) & 3) * 1024      // nt subtile
                + (d8 >> 2) * 512             // half = d>>5
                + (d8 & 3) * 128              // quad = (d>>3)&3
                + tok * 8;                    // l15 = key&15
            *(bf16x8*)dst = v;
        }
    }
}

// ---------------------------------------------------------------------------
// Kernel 2: flash attention, split-K, fixed-bound softmax (no online max).
// Barrier-free streaming: K fragments direct from global in MFMA-permuted
// layout (coalesced 1KB instructions, register-prefetched one tile ahead);
// V fragments ALSO direct from global in permuted layout (8 KB tile is
// L1-resident across the block's 4 waves x 8 reads — LDS staging and its
// vmcnt(0)-draining barriers were pure overhead). No __syncthreads anywhere:
// waves free-run, latency hidden by in-wave prefetch + 12 waves/CU.
// PV via mfma 16x16x16bf16_1k (B-layout == QK C-layout; no P transpose).
// Partial ctx bf16 via per-wave LDS transpose -> coalesced 16B stores.
// grid = SPLIT x 256; block = 64 q (wave owns 16), 16 k-tiles of 64 keys.
// ---------------------------------------------------------------------------
__global__ __launch_bounds__(256, 3) void attn_kernel(
    const __bf16* __restrict__ Qws, const __bf16* __restrict__ Kws,
    const __bf16* __restrict__ VTws,
    __bf16* __restrict__ Ops, float* __restrict__ Lws)
{
    // epilogue transpose scratch only: per-wave private region, no barriers
    __shared__ __align__(16) __bf16 tbuf[4 * 1088];

    const int bid   = blockIdx.x;
    const int split = bid >> 8;
    const int qt    = bid & 255;
    const int b  = qt >> 6;
    const int l0 = (qt & 63) << 6;
    const int t    = threadIdx.x;
    const int w    = t >> 6;
    const int lane = t & 63;
    const int quad = lane >> 4;
    const int l15  = lane & 15;

    // Q fragments (q = l15), pre-scaled by 0.125*log2e
    const __bf16* qptr = Qws + ((size_t)(b * 4096 + l0 + w * 16 + l15)) * 64 + quad * 8;
    bf16x8 qf0 = *(const bf16x8*)qptr;
    bf16x8 qf1 = *(const bf16x8*)(qptr + 32);

    f32x4 cfr[4];
    #pragma unroll
    for (int mt = 0; mt < 4; ++mt)
        #pragma unroll
        for (int r = 0; r < 4; ++r) cfr[mt][r] = 0.f;
    float l_run = 0.f;

    // K direct-global, permuted layout: per-lane offset lane*8 (coalesced)
    const __bf16* Kgl = Kws + ((size_t)b << 18)
                      + (size_t)(split * 16) * 4096 + lane * 8;
    // V direct-global, permuted layout (unswizzled — XOR was LDS-bank only):
    // element offset within tile = d*64 + (2*quad+kc8)*8,  d = mt*16+l15
    const __bf16* Vgl = VTws + ((size_t)b << 18)
                      + (size_t)(split * 16) * 4096 + l15 * 64 + quad * 16;

    union B4 { bf16x4 h; s16x4 s; };
    union V8 { bf16x8 v; s16x4 q[2]; };

    bf16x8 kfA[4][2], kfB[4][2];
    auto loadK = [&](bf16x8 (*kf)[2], int kt) {
        const __bf16* p = Kgl + (size_t)kt * 4096;
        #pragma unroll
        for (int nt = 0; nt < 4; ++nt) {
            kf[nt][0] = *(const bf16x8*)(p + nt * 1024);
            kf[nt][1] = *(const bf16x8*)(p + nt * 1024 + 512);
        }
    };

    auto tile_step = [&](int kt, bf16x8 (*kf)[2]) {
        // ---- V fragment loads issued first: consumed ~QK+exp later --------
        const __bf16* vp = Vgl + (size_t)kt * 4096;
        V8 vv[2][4];
        #pragma unroll
        for (int kc8 = 0; kc8 < 2; ++kc8)
            #pragma unroll
            for (int mt = 0; mt < 4; ++mt)
                vv[kc8][mt].v = *(const bf16x8*)(vp + mt * 1024 + kc8 * 8);

        // ---- QK^T (A=K from regs, B=Q), C init = -BBOUND, p = exp2(s) -----
        B4 pk[4];                      // P in C-layout == B-layout of 16x16x16
        float ps[4];
        #pragma unroll
        for (int nt = 0; nt < 4; ++nt) {
            f32x4 a = {-BBOUND, -BBOUND, -BBOUND, -BBOUND};
            a = MFMA32(kf[nt][0], qf0, a);
            a = MFMA32(kf[nt][1], qf1, a);
            float p0 = EXP2F(a[0]), p1 = EXP2F(a[1]);
            float p2 = EXP2F(a[2]), p3 = EXP2F(a[3]);
            pk[nt].h[0] = (__bf16)p0; pk[nt].h[1] = (__bf16)p1;
            pk[nt].h[2] = (__bf16)p2; pk[nt].h[3] = (__bf16)p3;
            ps[nt] = (p0 + p1) + (p2 + p3);
        }
        float psum = (ps[0] + ps[1]) + (ps[2] + ps[3]);
        psum += __shfl_xor(psum, 16);
        psum += __shfl_xor(psum, 32);
        l_run += psum;

        // ---- PV: ctx^T += V^T · P^T (two MFMAs per V b128) ----------------
        #pragma unroll
        for (int kc8 = 0; kc8 < 2; ++kc8) {
            #pragma unroll
            for (int mt = 0; mt < 4; ++mt) {
                cfr[mt] = MFMA16K(vv[kc8][mt].q[0], pk[2 * kc8 + 0].s, cfr[mt]);
                cfr[mt] = MFMA16K(vv[kc8][mt].q[1], pk[2 * kc8 + 1].s, cfr[mt]);
            }
        }
    };

    // prologue: K frags tile 0 -> regs; then free-running 2-deep K prefetch
    loadK(kfA, 0);
    for (int kt2 = 0; kt2 < 8; ++kt2) {
        loadK(kfB, 2 * kt2 + 1);       // prefetch odd K frags
        tile_step(2 * kt2, kfA);
        if (kt2 < 7) loadK(kfA, 2 * kt2 + 2);
        tile_step(2 * kt2 + 1, kfB);
    }

    // epilogue: transpose ctx through per-wave LDS region so partial ctx
    // goes out as coalesced bf16 16B stores (full 128B lines per row).
    // Within-wave write->read ordering is by lgkmcnt; no barrier needed.
    {
        __bf16* tb = tbuf + w * 1088;              // 16 rows x stride 68
        #pragma unroll
        for (int mt = 0; mt < 4; ++mt) {
            bf16x4 v;
            #pragma unroll
            for (int r = 0; r < 4; ++r) v[r] = (__bf16)cfr[mt][r];
            *(bf16x4*)&tb[l15 * 68 + mt * 16 + quad * 4] = v;
        }
        const int rowbase = (split * 4 + b) * 4096 + l0 + w * 16;
        #pragma unroll
        for (int h = 0; h < 2; ++h) {
            const int chunk = lane + h * 64;       // 0..127
            const int tok = chunk >> 3, c8 = chunk & 7;
            bf16x8 v = *(const bf16x8*)&tb[tok * 68 + c8 * 8];
            *(bf16x8*)(Ops + (size_t)(rowbase + tok) * 64 + c8 * 8) = v;
        }
        if (quad == 0) Lws[rowbase + l15] = l_run;
    }
}

// ---------------------------------------------------------------------------
// Kernel 3: split-combine (pure sum, bf16 partials) + output projection
// (bf16 MFMA) + bias + residual. grid = 1024 (b x 256 x 16 tok).
// ---------------------------------------------------------------------------
__global__ __launch_bounds__(256) void outproj_kernel(
    const float* __restrict__ inpt,
    const __bf16* __restrict__ Ops, const float* __restrict__ Lws,
    const float* __restrict__ Wo, const float* __restrict__ bo,
    float* __restrict__ out)
{
    __shared__ __align__(16) __bf16 cx[16 * 72];    // combined ctx [tok][d]
    const int bid = blockIdx.x;
    const int b   = bid >> 8;
    const int l0  = (bid & 255) << 4;
    const int t   = threadIdx.x;

    // combine: thread (token = t>>4, d4 = (t&15)*4); partials sum directly
    {
        const int token = t >> 4, d4 = (t & 15) << 2;
        const int rowb  = b * 4096 + l0 + token;
        float denom = 0.f;
        #pragma unroll
        for (int s = 0; s < SPLIT; ++s) denom += Lws[s * 16384 + rowb];
        const float inv = 1.f / denom;
        float ax = 0.f, ay = 0.f, az = 0.f, aw = 0.f;
        #pragma unroll
        for (int s = 0; s < SPLIT; ++s) {
            const bf16x4 v = *(const bf16x4*)(Ops
                + ((size_t)(s * 16384 + rowb)) * 64 + d4);
            ax += (float)v[0]; ay += (float)v[1];
            az += (float)v[2]; aw += (float)v[3];
        }
        bf16x4 pv;
        pv[0] = (__bf16)(ax * inv); pv[1] = (__bf16)(ay * inv);
        pv[2] = (__bf16)(az * inv); pv[3] = (__bf16)(aw * inv);
        *(bf16x4*)&cx[token * 72 + d4] = pv;
    }
    __syncthreads();

    const int w    = t >> 6;
    const int lane = t & 63;
    const int quad = lane >> 4;
    const int l15  = lane & 15;

    f32x4 acc[2];
    #pragma unroll
    for (int mi = 0; mi < 2; ++mi)
        #pragma unroll
        for (int r = 0; r < 4; ++r) acc[mi][r] = 0.f;

    #pragma unroll
    for (int ks = 0; ks < 2; ++ks) {
        bf16x8 bfrag = *(const bf16x8*)&cx[l15 * 72 + ks * 32 + quad * 8];  // B[n=tok][k=d]
        #pragma unroll
        for (int mi = 0; mi < 2; ++mi) {
            const int crow = (w * 2 + mi) * 16 + l15;
            const float* Wp = Wo + crow * 64 + ks * 32 + quad * 8;
            float4 wa = *(const float4*)Wp;
            float4 wb = *(const float4*)(Wp + 4);
            bf16x8 afrag;
            afrag[0] = (__bf16)wa.x; afrag[1] = (__bf16)wa.y;
            afrag[2] = (__bf16)wa.z; afrag[3] = (__bf16)wa.w;
            afrag[4] = (__bf16)wb.x; afrag[5] = (__bf16)wb.y;
            afrag[6] = (__bf16)wb.z; afrag[7] = (__bf16)wb.w;
            acc[mi] = MFMA32(afrag, bfrag, acc[mi]);     // D[m=c][n=tok]
        }
    }

    // epilogue: rows (quad*4+r) = c offset, col l15 = token
    #pragma unroll
    for (int mi = 0; mi < 2; ++mi) {
        #pragma unroll
        for (int r = 0; r < 4; ++r) {
            const int c = (w * 2 + mi) * 16 + quad * 4 + r;
            const size_t addr = ((size_t)(b * 128 + c)) * 4096 + l0 + l15;
            out[addr] = inpt[addr] + bo[c] + acc[mi][r];
        }
    }
}

// ---------------------------------------------------------------------------
extern "C" void kernel_launch(void* const* d_in, const int* in_sizes, int n_in,
                              void* d_out, int out_size, void* d_ws, size_t ws_size,
                              hipStream_t stream)
{
    const float* inpt = (const float*)d_in[0];
    const float* Wq   = (const float*)d_in[1];
    const float* bq   = (const float*)d_in[2];
    const float* Wk   = (const float*)d_in[3];
    const float* bk   = (const float*)d_in[4];
    const float* Wv   = (const float*)d_in[5];
    const float* bv   = (const float*)d_in[6];
    const float* Wo   = (const float*)d_in[7];
    const float* bo   = (const float*)d_in[8];
    float* out = (float*)d_out;

    char* ws = (char*)d_ws;
    const size_t MB = (size_t)1 << 20;
    __bf16* Qws  = (__bf16*)(ws + 0 * MB);
    __bf16* Kws  = (__bf16*)(ws + 2 * MB);         // MFMA-permuted tile layout
    __bf16* VTws = (__bf16*)(ws + 4 * MB);         // permuted tile layout
    __bf16* Ops  = (__bf16*)(ws + 6 * MB);         // SPLIT(4) x 2.1MB = 8.4 MB
    float*  Lws  = (float*)(ws + 16 * MB);         // 256 KB

    qkv_kernel<<<1024, 256, 0, stream>>>(inpt, Wq, bq, Wk, bk, Wv, bv, Qws, Kws, VTws);
    attn_kernel<<<SPLIT * 256, 256, 0, stream>>>(Qws, Kws, VTws, Ops, Lws);
    outproj_kernel<<<1024, 256, 0, stream>>>(inpt, Ops, Lws, Wo, bo, out);
}

// Round 2
// 125.534 us; speedup vs baseline: 1.3714x; 1.3714x over previous
//
#include <hip/hip_runtime.h>
#include <hip/hip_bf16.h>

typedef __bf16 bf16x8 __attribute__((ext_vector_type(8)));
typedef __bf16 bf16x4 __attribute__((ext_vector_type(4)));
typedef short  s16x4  __attribute__((ext_vector_type(4)));
typedef float  f32x4  __attribute__((ext_vector_type(4)));

#define MFMA32(a, b, c) __builtin_amdgcn_mfma_f32_16x16x32_bf16((a), (b), (c), 0, 0, 0)
#define MFMA16K(a, b, c) __builtin_amdgcn_mfma_f32_16x16x16bf16_1k((a), (b), (c), 0, 0, 0)

#if __has_builtin(__builtin_amdgcn_exp2f)
#define EXP2F(x) __builtin_amdgcn_exp2f(x)
#else
#define EXP2F(x) __expf(0.6931471805599453f * (x))
#endif

// async global->LDS, 16B per lane. LDS dest must be wave-uniform base.
#define GL16(G, L)                                                            \
    __builtin_amdgcn_global_load_lds(                                         \
        (const __attribute__((address_space(1))) void*)(G),                   \
        (__attribute__((address_space(3))) void*)(L), 16, 0, 0)

#define SPLIT 4
// BS=4, C=128, L=4096, D=64. Q pre-scaled by 0.125*log2(e): softmax in base 2.
// Fixed-bound softmax: p = 2^(s - BBOUND); the 2^(m-B) factor cancels in the
// final normalization. BBOUND folded into QK MFMA accumulator init.
#define QSCALE 0.18033688011112042f
#define BBOUND 12.0f

// K workspace layout (MFMA-permuted, per 64-key tile contiguous 8 KB):
//   Kp[b][kt][nt][half][quad][l15][i]   (key = nt*16+l15, d = half*32+quad*8+i)
// V workspace layout (permuted, per 64-key tile contiguous 8 KB):
//   Vp[b][kt][d][quad][kc][i]  (quad=key>>2&3, kc=key>>4, i=key&3)

// ---------------------------------------------------------------------------
// Kernel 1: QKV projection, bf16 MFMA. grid = 1024 (b x 256 tiles of 16 tok).
// ---------------------------------------------------------------------------
__global__ __launch_bounds__(256) void qkv_kernel(
    const float* __restrict__ inpt,
    const float* __restrict__ Wq, const float* __restrict__ bq,
    const float* __restrict__ Wk, const float* __restrict__ bk,
    const float* __restrict__ Wv, const float* __restrict__ bv,
    __bf16* __restrict__ Qws, __bf16* __restrict__ Kws, __bf16* __restrict__ VTws)
{
    __shared__ __align__(16) __bf16 xT[16 * 140];   // [tok][c]
    __shared__ __align__(16) __bf16 os[16 * 144];   // [tok][qk-out 0..127]
    const int bid = blockIdx.x;
    const int b   = bid >> 8;
    const int l0  = (bid & 255) << 4;               // 16 tokens
    const int t   = threadIdx.x;

    // stage x^T: thread (c = t>>1, half = t&1) loads 8 floats of row c
    {
        const int c = t >> 1, half = t & 1;
        const float* xin = inpt + ((size_t)(b * 128 + c)) * 4096 + l0 + half * 8;
        float4 v0 = *(const float4*)xin;
        float4 v1 = *(const float4*)(xin + 4);
        const int tok0 = half * 8;
        xT[(tok0 + 0) * 140 + c] = (__bf16)v0.x;
        xT[(tok0 + 1) * 140 + c] = (__bf16)v0.y;
        xT[(tok0 + 2) * 140 + c] = (__bf16)v0.z;
        xT[(tok0 + 3) * 140 + c] = (__bf16)v0.w;
        xT[(tok0 + 4) * 140 + c] = (__bf16)v1.x;
        xT[(tok0 + 5) * 140 + c] = (__bf16)v1.y;
        xT[(tok0 + 6) * 140 + c] = (__bf16)v1.z;
        xT[(tok0 + 7) * 140 + c] = (__bf16)v1.w;
    }
    __syncthreads();

    const int w    = t >> 6;
    const int lane = t & 63;
    const int quad = lane >> 4;
    const int l15  = lane & 15;

    f32x4 acc[3];
    #pragma unroll
    for (int j = 0; j < 3; ++j)
        #pragma unroll
        for (int r = 0; r < 4; ++r) acc[j][r] = 0.f;

    #pragma unroll
    for (int ks = 0; ks < 4; ++ks) {
        bf16x8 af = *(const bf16x8*)&xT[l15 * 140 + ks * 32 + quad * 8];
        #pragma unroll
        for (int j = 0; j < 3; ++j) {
            const int wn   = w * 3 + j;                 // n-tile 0..11
            const int msel = wn >> 2;                   // 0=Q 1=K 2=V
            const float* W = (msel == 0) ? Wq : ((msel == 1) ? Wk : Wv);
            const float* Wp = W + ((wn & 3) * 16 + l15) * 128 + ks * 32 + quad * 8;
            float4 wa = *(const float4*)Wp;
            float4 wb = *(const float4*)(Wp + 4);
            bf16x8 bf;
            bf[0] = (__bf16)wa.x; bf[1] = (__bf16)wa.y;
            bf[2] = (__bf16)wa.z; bf[3] = (__bf16)wa.w;
            bf[4] = (__bf16)wb.x; bf[5] = (__bf16)wb.y;
            bf[6] = (__bf16)wb.z; bf[7] = (__bf16)wb.w;
            acc[j] = MFMA32(af, bf, acc[j]);            // D[m=tok][n=out]
        }
    }

    // epilogue: D rows (quad*4+r) = token, col l15 = output within n-tile
    #pragma unroll
    for (int j = 0; j < 3; ++j) {
        const int wn   = w * 3 + j;
        const int msel = wn >> 2;
        const int o0   = (wn & 3) * 16;
        const float* bb = (msel == 0) ? bq : ((msel == 1) ? bk : bv);
        float bias = bb[o0 + l15];
        if (msel < 2) {
            const float scl = (msel == 0) ? QSCALE : 1.0f;
            const int oc = wn * 16 + l15;               // 0..127
            #pragma unroll
            for (int r = 0; r < 4; ++r)
                os[(quad * 4 + r) * 144 + oc] = (__bf16)((acc[j][r] + bias) * scl);
        } else {
            const int d  = o0 + l15;
            const int kt = l0 >> 6;
            const int kc = (l0 >> 4) & 3;
            bf16x4 v;
            #pragma unroll
            for (int r = 0; r < 4; ++r) v[r] = (__bf16)(acc[j][r] + bias);
            *(bf16x4*)(VTws + (size_t)b * 262144 + kt * 4096
                       + d * 64 + quad * 16 + kc * 4) = v;
        }
    }
    __syncthreads();

    // Q store coalesced [l][64]; K store to the MFMA-permuted tile layout.
    {
        const int tok = t >> 4, c = t & 15;
        bf16x8 v = *(const bf16x8*)&os[tok * 144 + c * 8];
        if (c < 8) {
            *(bf16x8*)(Qws + ((size_t)(b * 4096 + l0 + tok)) * 64 + c * 8) = v;
        } else {
            const int d8 = c - 8;                       // d = d8*8 .. +7
            __bf16* dst = Kws + (size_t)b * 262144
                + (l0 >> 6) * 4096            // tile
                + ((l0 >> 4) & 3) * 1024      // nt subtile
                + (d8 >> 2) * 512             // half = d>>5
                + (d8 & 3) * 128              // quad = (d>>3)&3
                + tok * 8;                    // l15 = key&15
            *(bf16x8*)dst = v;
        }
    }
}

// ---------------------------------------------------------------------------
// Kernel 2: flash attention, split-K, fixed-bound softmax (no online max).
// Pipelined with COUNTED vmcnt + raw s_barrier (T3/T4): V staged into a
// ring-3 LDS buffer via global_load_lds (2 compute-phases of flight), K
// fragments double-buffered in registers, prefetch pinned by the
// "memory"-clobbered waitcnt asm so the compiler cannot sink the loads.
// At every barrier the newest 10 VMEM ops (next V stage = 2 GL16 + next K
// group = 8 loads) stay in flight; vmcnt(10) guarantees the current tile's
// V stage (and everything older) has landed. Ring slot s is only re-staged
// after a barrier that follows all waves' reads of s (write-after-read safe).
// grid = SPLIT x 256; block = 64 q (wave owns 16), 16 k-tiles of 64 keys.
// ---------------------------------------------------------------------------
__global__ __launch_bounds__(256, 4) void attn_kernel(
    const __bf16* __restrict__ Qws, const __bf16* __restrict__ Kws,
    const __bf16* __restrict__ VTws,
    __bf16* __restrict__ Ops, float* __restrict__ Lws)
{
    __shared__ __align__(16) __bf16 sbuf[3][4096];   // V ring, 8 KB/slot

    const int bid   = blockIdx.x;
    const int split = bid >> 8;
    const int qt    = bid & 255;
    const int b  = qt >> 6;
    const int l0 = (qt & 63) << 6;
    const int t    = threadIdx.x;
    const int w    = t >> 6;
    const int lane = t & 63;
    const int quad = lane >> 4;
    const int l15  = lane & 15;

    // Q fragments (q = l15), pre-scaled by 0.125*log2e
    const __bf16* qptr = Qws + ((size_t)(b * 4096 + l0 + w * 16 + l15)) * 64 + quad * 8;
    bf16x8 qf0 = *(const bf16x8*)qptr;
    bf16x8 qf1 = *(const bf16x8*)(qptr + 32);

    f32x4 cfr[4];
    #pragma unroll
    for (int mt = 0; mt < 4; ++mt)
        #pragma unroll
        for (int r = 0; r < 4; ++r) cfr[mt][r] = 0.f;
    float l_run = 0.f;

    // hoisted V LDS element offsets (loop-invariant across tiles)
    int voff[8];
    #pragma unroll
    for (int mt = 0; mt < 4; ++mt) {
        const int d = mt * 16 + l15;
        #pragma unroll
        for (int kc8 = 0; kc8 < 2; ++kc8)
            voff[kc8 * 4 + mt] = d * 64 + (((2 * quad + kc8) ^ (d & 7)) * 8);
    }

    // V staging source pointer (swizzled 16B chunks; LDS dest stays linear)
    const uint4* Vg = (const uint4*)(VTws + ((size_t)b << 18));
    const int rw = t >> 3, cw = (t & 7) ^ ((t >> 3) & 7);
    const uint4* vbase = Vg + rw * 8 + cw + split * 8192;

    // K direct-global, permuted layout: per-lane offset lane*8 (coalesced)
    const __bf16* Kgl = Kws + ((size_t)b << 18)
                      + (size_t)(split * 16) * 4096 + lane * 8;

    union B4 { bf16x4 h; s16x4 s; };
    union V8 { bf16x8 v; s16x4 q[2]; };

    auto stageV = [&](int kt, int slot) {               // 2 GL16 per thread
        __bf16* Bb = &sbuf[slot][0];
        const uint4* vp = vbase + (size_t)kt * 512;
        GL16(vp,       Bb +        w * 512);
        GL16(vp + 256, Bb + 2048 + w * 512);
    };

    bf16x8 kfA[4][2], kfB[4][2];
    auto loadK = [&](bf16x8 (*kf)[2], int kt) {         // 8 loads per thread
        const __bf16* p = Kgl + (size_t)kt * 4096;
        #pragma unroll
        for (int nt = 0; nt < 4; ++nt) {
            kf[nt][0] = *(const bf16x8*)(p + nt * 1024);
            kf[nt][1] = *(const bf16x8*)(p + nt * 1024 + 512);
        }
    };

    auto tile_step = [&](const __bf16* __restrict__ B, bf16x8 (*kf)[2]) {
        // ---- QK^T (A=K from regs, B=Q), C init = -BBOUND, p = exp2(s) -----
        B4 pk[4];                      // P in C-layout == B-layout of 16x16x16
        float ps[4];
        #pragma unroll
        for (int nt = 0; nt < 4; ++nt) {
            f32x4 a = {-BBOUND, -BBOUND, -BBOUND, -BBOUND};
            a = MFMA32(kf[nt][0], qf0, a);
            a = MFMA32(kf[nt][1], qf1, a);
            float p0 = EXP2F(a[0]), p1 = EXP2F(a[1]);
            float p2 = EXP2F(a[2]), p3 = EXP2F(a[3]);
            pk[nt].h[0] = (__bf16)p0; pk[nt].h[1] = (__bf16)p1;
            pk[nt].h[2] = (__bf16)p2; pk[nt].h[3] = (__bf16)p3;
            ps[nt] = (p0 + p1) + (p2 + p3);
        }
        float psum = (ps[0] + ps[1]) + (ps[2] + ps[3]);
        psum += __shfl_xor(psum, 16);
        psum += __shfl_xor(psum, 32);
        l_run += psum;

        // ---- PV: ctx^T += V^T · P^T (b128 V reads, two MFMAs per read) ----
        #pragma unroll
        for (int kc8 = 0; kc8 < 2; ++kc8) {
            #pragma unroll
            for (int mt = 0; mt < 4; ++mt) {
                V8 vv;
                vv.v = *(const bf16x8*)&B[voff[kc8 * 4 + mt]];
                cfr[mt] = MFMA16K(vv.q[0], pk[2 * kc8 + 0].s, cfr[mt]);
                cfr[mt] = MFMA16K(vv.q[1], pk[2 * kc8 + 1].s, cfr[mt]);
            }
        }
    };

    // counted wait: everything except the newest 10 VMEM ops has completed;
    // then barrier; then a compiler fence so stage/loads can't hoist above.
#define WAITBAR()                                                             \
    do {                                                                      \
        asm volatile("s_waitcnt vmcnt(10)" ::: "memory");                     \
        __builtin_amdgcn_s_barrier();                                         \
        asm volatile("" ::: "memory");                                        \
    } while (0)

    // prologue: V tiles 0,1 -> slots 0,1; K frags tile 0 -> regs
    stageV(0, 0);
    stageV(1, 1);
    loadK(kfA, 0);

    int cons = 0;                      // ring slot being consumed (= h % 3)
    int stg  = 2;                      // ring slot being staged  (= (h+2) % 3)
    for (int kt2 = 0; kt2 < 8; ++kt2) {
        const int h0 = 2 * kt2;
        // ---- even tile h0: V slot cons, K in kfA ----
        WAITBAR();                               // V_h0 landed (all waves)
        if (kt2 < 7) stageV(h0 + 2, stg);        // prefetch V two tiles ahead
        loadK(kfB, h0 + 1);                      // prefetch K one tile ahead
        tile_step(&sbuf[cons][0], kfA);
        cons = (cons == 2) ? 0 : cons + 1;
        stg  = (stg  == 2) ? 0 : stg  + 1;
        // ---- odd tile h0+1: V slot cons, K in kfB ----
        WAITBAR();                               // V_h1 landed
        if (kt2 < 7) { stageV(h0 + 3, stg); loadK(kfA, h0 + 2); }
        tile_step(&sbuf[cons][0], kfB);
        cons = (cons == 2) ? 0 : cons + 1;
        stg  = (stg  == 2) ? 0 : stg  + 1;
    }
#undef WAITBAR

    // all waves done reading the ring before it is reused as transpose scratch
    __builtin_amdgcn_s_barrier();
    asm volatile("" ::: "memory");

    // epilogue: transpose ctx through per-wave LDS region so partial ctx
    // goes out as coalesced bf16 16B stores (full 128B lines per row).
    {
        __bf16* tb = (__bf16*)sbuf + w * 1088;     // 16 rows x stride 68
        #pragma unroll
        for (int mt = 0; mt < 4; ++mt) {
            bf16x4 v;
            #pragma unroll
            for (int r = 0; r < 4; ++r) v[r] = (__bf16)cfr[mt][r];
            *(bf16x4*)&tb[l15 * 68 + mt * 16 + quad * 4] = v;
        }
        const int rowbase = (split * 4 + b) * 4096 + l0 + w * 16;
        #pragma unroll
        for (int h = 0; h < 2; ++h) {
            const int chunk = lane + h * 64;       // 0..127
            const int tok = chunk >> 3, c8 = chunk & 7;
            bf16x8 v = *(const bf16x8*)&tb[tok * 68 + c8 * 8];
            *(bf16x8*)(Ops + (size_t)(rowbase + tok) * 64 + c8 * 8) = v;
        }
        if (quad == 0) Lws[rowbase + l15] = l_run;
    }
}

// ---------------------------------------------------------------------------
// Kernel 3: split-combine (pure sum, bf16 partials) + output projection
// (bf16 MFMA) + bias + residual. grid = 1024 (b x 256 x 16 tok).
// ---------------------------------------------------------------------------
__global__ __launch_bounds__(256) void outproj_kernel(
    const float* __restrict__ inpt,
    const __bf16* __restrict__ Ops, const float* __restrict__ Lws,
    const float* __restrict__ Wo, const float* __restrict__ bo,
    float* __restrict__ out)
{
    __shared__ __align__(16) __bf16 cx[16 * 72];    // combined ctx [tok][d]
    const int bid = blockIdx.x;
    const int b   = bid >> 8;
    const int l0  = (bid & 255) << 4;
    const int t   = threadIdx.x;

    // combine: thread (token = t>>4, d4 = (t&15)*4); partials sum directly
    {
        const int token = t >> 4, d4 = (t & 15) << 2;
        const int rowb  = b * 4096 + l0 + token;
        float denom = 0.f;
        #pragma unroll
        for (int s = 0; s < SPLIT; ++s) denom += Lws[s * 16384 + rowb];
        const float inv = 1.f / denom;
        float ax = 0.f, ay = 0.f, az = 0.f, aw = 0.f;
        #pragma unroll
        for (int s = 0; s < SPLIT; ++s) {
            const bf16x4 v = *(const bf16x4*)(Ops
                + ((size_t)(s * 16384 + rowb)) * 64 + d4);
            ax += (float)v[0]; ay += (float)v[1];
            az += (float)v[2]; aw += (float)v[3];
        }
        bf16x4 pv;
        pv[0] = (__bf16)(ax * inv); pv[1] = (__bf16)(ay * inv);
        pv[2] = (__bf16)(az * inv); pv[3] = (__bf16)(aw * inv);
        *(bf16x4*)&cx[token * 72 + d4] = pv;
    }
    __syncthreads();

    const int w    = t >> 6;
    const int lane = t & 63;
    const int quad = lane >> 4;
    const int l15  = lane & 15;

    f32x4 acc[2];
    #pragma unroll
    for (int mi = 0; mi < 2; ++mi)
        #pragma unroll
        for (int r = 0; r < 4; ++r) acc[mi][r] = 0.f;

    #pragma unroll
    for (int ks = 0; ks < 2; ++ks) {
        bf16x8 bfrag = *(const bf16x8*)&cx[l15 * 72 + ks * 32 + quad * 8];  // B[n=tok][k=d]
        #pragma unroll
        for (int mi = 0; mi < 2; ++mi) {
            const int crow = (w * 2 + mi) * 16 + l15;
            const float* Wp = Wo + crow * 64 + ks * 32 + quad * 8;
            float4 wa = *(const float4*)Wp;
            float4 wb = *(const float4*)(Wp + 4);
            bf16x8 afrag;
            afrag[0] = (__bf16)wa.x; afrag[1] = (__bf16)wa.y;
            afrag[2] = (__bf16)wa.z; afrag[3] = (__bf16)wa.w;
            afrag[4] = (__bf16)wb.x; afrag[5] = (__bf16)wb.y;
            afrag[6] = (__bf16)wb.z; afrag[7] = (__bf16)wb.w;
            acc[mi] = MFMA32(afrag, bfrag, acc[mi]);     // D[m=c][n=tok]
        }
    }

    // epilogue: rows (quad*4+r) = c offset, col l15 = token
    #pragma unroll
    for (int mi = 0; mi < 2; ++mi) {
        #pragma unroll
        for (int r = 0; r < 4; ++r) {
            const int c = (w * 2 + mi) * 16 + quad * 4 + r;
            const size_t addr = ((size_t)(b * 128 + c)) * 4096 + l0 + l15;
            out[addr] = inpt[addr] + bo[c] + acc[mi][r];
        }
    }
}

// ---------------------------------------------------------------------------
extern "C" void kernel_launch(void* const* d_in, const int* in_sizes, int n_in,
                              void* d_out, int out_size, void* d_ws, size_t ws_size,
                              hipStream_t stream)
{
    const float* inpt = (const float*)d_in[0];
    const float* Wq   = (const float*)d_in[1];
    const float* bq   = (const float*)d_in[2];
    const float* Wk   = (const float*)d_in[3];
    const float* bk   = (const float*)d_in[4];
    const float* Wv   = (const float*)d_in[5];
    const float* bv   = (const float*)d_in[6];
    const float* Wo   = (const float*)d_in[7];
    const float* bo   = (const float*)d_in[8];
    float* out = (float*)d_out;

    char* ws = (char*)d_ws;
    const size_t MB = (size_t)1 << 20;
    __bf16* Qws  = (__bf16*)(ws + 0 * MB);
    __bf16* Kws  = (__bf16*)(ws + 2 * MB);         // MFMA-permuted tile layout
    __bf16* VTws = (__bf16*)(ws + 4 * MB);         // permuted tile layout
    __bf16* Ops  = (__bf16*)(ws + 6 * MB);         // SPLIT(4) x 2.1MB = 8.4 MB
    float*  Lws  = (float*)(ws + 16 * MB);         // 256 KB

    qkv_kernel<<<1024, 256, 0, stream>>>(inpt, Wq, bq, Wk, bk, Wv, bv, Qws, Kws, VTws);
    attn_kernel<<<SPLIT * 256, 256, 0, stream>>>(Qws, Kws, VTws, Ops, Lws);
    outproj_kernel<<<1024, 256, 0, stream>>>(inpt, Ops, Lws, Wo, bo, out);
}

// Round 3
// 124.977 us; speedup vs baseline: 1.3775x; 1.0045x over previous
//
#include <hip/hip_runtime.h>
#include <hip/hip_bf16.h>

typedef __bf16 bf16x8 __attribute__((ext_vector_type(8)));
typedef __bf16 bf16x4 __attribute__((ext_vector_type(4)));
typedef short  s16x4  __attribute__((ext_vector_type(4)));
typedef float  f32x4  __attribute__((ext_vector_type(4)));

#define MFMA32(a, b, c) __builtin_amdgcn_mfma_f32_16x16x32_bf16((a), (b), (c), 0, 0, 0)
#define MFMA16K(a, b, c) __builtin_amdgcn_mfma_f32_16x16x16bf16_1k((a), (b), (c), 0, 0, 0)

#if __has_builtin(__builtin_amdgcn_exp2f)
#define EXP2F(x) __builtin_amdgcn_exp2f(x)
#else
#define EXP2F(x) __expf(0.6931471805599453f * (x))
#endif

// async global->LDS, 16B per lane. LDS dest must be wave-uniform base.
#define GL16(G, L)                                                            \
    __builtin_amdgcn_global_load_lds(                                         \
        (const __attribute__((address_space(1))) void*)(G),                   \
        (__attribute__((address_space(3))) void*)(L), 16, 0, 0)

#define SPLIT 8
// BS=4, C=128, L=4096, D=64. Q pre-scaled by 0.125*log2(e): softmax in base 2.
// Fixed-bound softmax: p = 2^(s - BBOUND); the 2^(m-B) factor cancels in the
// final normalization. BBOUND folded into QK MFMA accumulator init.
#define QSCALE 0.18033688011112042f
#define BBOUND 12.0f

// K workspace layout (MFMA-permuted, per 64-key tile contiguous 8 KB):
//   Kp[b][kt][nt][half][lane][i]   (key = nt*16+(lane&15), d = half*32+(lane>>4)*8+i)
// V workspace layout (permuted, per 64-key tile contiguous 8 KB):
//   Vp[b][kt][d][quad][kc][i]  (quad=key>>2&3, kc=key>>4, i=key&3)

// ---------------------------------------------------------------------------
// Kernel 1: QKV projection, bf16 MFMA. grid = 1024 (b x 256 tiles of 16 tok).
// ---------------------------------------------------------------------------
__global__ __launch_bounds__(256) void qkv_kernel(
    const float* __restrict__ inpt,
    const float* __restrict__ Wq, const float* __restrict__ bq,
    const float* __restrict__ Wk, const float* __restrict__ bk,
    const float* __restrict__ Wv, const float* __restrict__ bv,
    __bf16* __restrict__ Qws, __bf16* __restrict__ Kws, __bf16* __restrict__ VTws)
{
    __shared__ __align__(16) __bf16 xT[16 * 140];   // [tok][c]
    __shared__ __align__(16) __bf16 os[16 * 144];   // [tok][qk-out 0..127]
    const int bid = blockIdx.x;
    const int b   = bid >> 8;
    const int l0  = (bid & 255) << 4;               // 16 tokens
    const int t   = threadIdx.x;

    // stage x^T: thread (c = t>>1, half = t&1) loads 8 floats of row c
    {
        const int c = t >> 1, half = t & 1;
        const float* xin = inpt + ((size_t)(b * 128 + c)) * 4096 + l0 + half * 8;
        float4 v0 = *(const float4*)xin;
        float4 v1 = *(const float4*)(xin + 4);
        const int tok0 = half * 8;
        xT[(tok0 + 0) * 140 + c] = (__bf16)v0.x;
        xT[(tok0 + 1) * 140 + c] = (__bf16)v0.y;
        xT[(tok0 + 2) * 140 + c] = (__bf16)v0.z;
        xT[(tok0 + 3) * 140 + c] = (__bf16)v0.w;
        xT[(tok0 + 4) * 140 + c] = (__bf16)v1.x;
        xT[(tok0 + 5) * 140 + c] = (__bf16)v1.y;
        xT[(tok0 + 6) * 140 + c] = (__bf16)v1.z;
        xT[(tok0 + 7) * 140 + c] = (__bf16)v1.w;
    }
    __syncthreads();

    const int w    = t >> 6;
    const int lane = t & 63;
    const int quad = lane >> 4;
    const int l15  = lane & 15;

    f32x4 acc[3];
    #pragma unroll
    for (int j = 0; j < 3; ++j)
        #pragma unroll
        for (int r = 0; r < 4; ++r) acc[j][r] = 0.f;

    #pragma unroll
    for (int ks = 0; ks < 4; ++ks) {
        bf16x8 af = *(const bf16x8*)&xT[l15 * 140 + ks * 32 + quad * 8];
        #pragma unroll
        for (int j = 0; j < 3; ++j) {
            const int wn   = w * 3 + j;                 // n-tile 0..11
            const int msel = wn >> 2;                   // 0=Q 1=K 2=V
            const float* W = (msel == 0) ? Wq : ((msel == 1) ? Wk : Wv);
            const float* Wp = W + ((wn & 3) * 16 + l15) * 128 + ks * 32 + quad * 8;
            float4 wa = *(const float4*)Wp;
            float4 wb = *(const float4*)(Wp + 4);
            bf16x8 bf;
            bf[0] = (__bf16)wa.x; bf[1] = (__bf16)wa.y;
            bf[2] = (__bf16)wa.z; bf[3] = (__bf16)wa.w;
            bf[4] = (__bf16)wb.x; bf[5] = (__bf16)wb.y;
            bf[6] = (__bf16)wb.z; bf[7] = (__bf16)wb.w;
            acc[j] = MFMA32(af, bf, acc[j]);            // D[m=tok][n=out]
        }
    }

    // epilogue: D rows (quad*4+r) = token, col l15 = output within n-tile
    #pragma unroll
    for (int j = 0; j < 3; ++j) {
        const int wn   = w * 3 + j;
        const int msel = wn >> 2;
        const int o0   = (wn & 3) * 16;
        const float* bb = (msel == 0) ? bq : ((msel == 1) ? bk : bv);
        float bias = bb[o0 + l15];
        if (msel < 2) {
            const float scl = (msel == 0) ? QSCALE : 1.0f;
            const int oc = wn * 16 + l15;               // 0..127
            #pragma unroll
            for (int r = 0; r < 4; ++r)
                os[(quad * 4 + r) * 144 + oc] = (__bf16)((acc[j][r] + bias) * scl);
        } else {
            const int d  = o0 + l15;
            const int kt = l0 >> 6;
            const int kc = (l0 >> 4) & 3;
            bf16x4 v;
            #pragma unroll
            for (int r = 0; r < 4; ++r) v[r] = (__bf16)(acc[j][r] + bias);
            *(bf16x4*)(VTws + (size_t)b * 262144 + kt * 4096
                       + d * 64 + quad * 16 + kc * 4) = v;
        }
    }
    __syncthreads();

    // Q store coalesced [l][64]; K store to the MFMA-permuted tile layout.
    {
        const int tok = t >> 4, c = t & 15;
        bf16x8 v = *(const bf16x8*)&os[tok * 144 + c * 8];
        if (c < 8) {
            *(bf16x8*)(Qws + ((size_t)(b * 4096 + l0 + tok)) * 64 + c * 8) = v;
        } else {
            const int d8 = c - 8;                       // d = d8*8 .. +7
            __bf16* dst = Kws + (size_t)b * 262144
                + (l0 >> 6) * 4096            // tile
                + ((l0 >> 4) & 3) * 1024      // nt subtile
                + (d8 >> 2) * 512             // half = d>>5
                + (d8 & 3) * 128              // quad = (d>>3)&3
                + tok * 8;                    // l15 = key&15
            *(bf16x8*)dst = v;
        }
    }
}

// ---------------------------------------------------------------------------
// Kernel 2: flash attention, split-K, fixed-bound softmax (no online max).
// NEW: 32 q-rows per wave (2 q-subtiles share every K/V fragment — halves
// per-wave fragment traffic per unit work) and K staged through LDS like V
// (global->LDS DMA once per block, not 4x per wave through L1). Ring-2
// K+V slots (16 KB/slot, 32 KB LDS, 4 blocks/CU). Staging issued right
// after the barrier -> one full compute phase of flight -> drained by
// vmcnt(0) just before the next barrier. setprio(1) around PV MFMA cluster.
// grid = SPLIT x 128; block = 128 q (wave owns 32), 8 k-tiles of 64 keys.
// ---------------------------------------------------------------------------
__global__ __launch_bounds__(256, 4) void attn_kernel(
    const __bf16* __restrict__ Qws, const __bf16* __restrict__ Kws,
    const __bf16* __restrict__ VTws,
    __bf16* __restrict__ Ops, float* __restrict__ Lws)
{
    // [slot][0..4096) = K tile, [slot][4096..8192) = V tile
    __shared__ __align__(16) __bf16 sbuf[2][8192];

    const int bid   = blockIdx.x;
    const int split = bid >> 7;
    const int qi    = bid & 127;
    const int b  = qi >> 5;
    const int l0 = (qi & 31) << 7;     // 128 q-rows per block
    const int t    = threadIdx.x;
    const int w    = t >> 6;
    const int lane = t & 63;
    const int quad = lane >> 4;
    const int l15  = lane & 15;

    // Q fragments for 2 subtiles (rows w*32 + qs*16 + l15), pre-scaled
    bf16x8 qf[2][2];
    #pragma unroll
    for (int qs = 0; qs < 2; ++qs) {
        const __bf16* qptr = Qws
            + ((size_t)(b * 4096 + l0 + w * 32 + qs * 16 + l15)) * 64 + quad * 8;
        qf[qs][0] = *(const bf16x8*)qptr;
        qf[qs][1] = *(const bf16x8*)(qptr + 32);
    }

    f32x4 cfr[2][4];
    #pragma unroll
    for (int qs = 0; qs < 2; ++qs)
        #pragma unroll
        for (int mt = 0; mt < 4; ++mt)
            #pragma unroll
            for (int r = 0; r < 4; ++r) cfr[qs][mt][r] = 0.f;
    float l_acc[2] = {0.f, 0.f};

    // hoisted V LDS element offsets (within V half of slot)
    int voff[8];
    #pragma unroll
    for (int mt = 0; mt < 4; ++mt) {
        const int d = mt * 16 + l15;
        #pragma unroll
        for (int kc8 = 0; kc8 < 2; ++kc8)
            voff[kc8 * 4 + mt] = d * 64 + (((2 * quad + kc8) ^ (d & 7)) * 8);
    }

    // staging source pointers (per-thread); LDS dests wave-uniform
    const uint4* Vg = (const uint4*)(VTws + ((size_t)b << 18));
    const int rw = t >> 3, cw = (t & 7) ^ ((t >> 3) & 7);
    const uint4* vbase = Vg + rw * 8 + cw + split * 4096;   // swizzled source
    const uint4* kbase = (const uint4*)(Kws + ((size_t)b << 18))
                       + t + split * 4096;                  // linear source

    union B4 { bf16x4 h; s16x4 s; };
    union V8 { bf16x8 v; s16x4 q[2]; };

    auto stage = [&](int kt, int slot) {                    // 4 GL16 / thread
        __bf16* Kd = &sbuf[slot][0];
        __bf16* Vd = &sbuf[slot][4096];
        const uint4* kp = kbase + kt * 512;
        const uint4* vp = vbase + kt * 512;
        GL16(kp,       Kd +        w * 512);
        GL16(kp + 256, Kd + 2048 + w * 512);
        GL16(vp,       Vd +        w * 512);
        GL16(vp + 256, Vd + 2048 + w * 512);
    };

    auto tile_step = [&](int slot) {
        const __bf16* Kb = &sbuf[slot][0];
        const __bf16* Vb = &sbuf[slot][4096];
        // ---- QK^T: K frags from LDS, shared across both q-subtiles -------
        B4 pk[2][4];
        #pragma unroll
        for (int nt = 0; nt < 4; ++nt) {
            bf16x8 k0 = *(const bf16x8*)(Kb + nt * 1024 +       lane * 8);
            bf16x8 k1 = *(const bf16x8*)(Kb + nt * 1024 + 512 + lane * 8);
            #pragma unroll
            for (int qs = 0; qs < 2; ++qs) {
                f32x4 a = {-BBOUND, -BBOUND, -BBOUND, -BBOUND};
                a = MFMA32(k0, qf[qs][0], a);
                a = MFMA32(k1, qf[qs][1], a);
                float p0 = EXP2F(a[0]), p1 = EXP2F(a[1]);
                float p2 = EXP2F(a[2]), p3 = EXP2F(a[3]);
                pk[qs][nt].h[0] = (__bf16)p0; pk[qs][nt].h[1] = (__bf16)p1;
                pk[qs][nt].h[2] = (__bf16)p2; pk[qs][nt].h[3] = (__bf16)p3;
                l_acc[qs] += (p0 + p1) + (p2 + p3);   // lane-local; reduce at end
            }
        }
        // ---- PV: each V b128 feeds 4 MFMAs (2 per q-subtile) --------------
        __builtin_amdgcn_s_setprio(1);
        #pragma unroll
        for (int kc8 = 0; kc8 < 2; ++kc8) {
            #pragma unroll
            for (int mt = 0; mt < 4; ++mt) {
                V8 vv;
                vv.v = *(const bf16x8*)&Vb[voff[kc8 * 4 + mt]];
                #pragma unroll
                for (int qs = 0; qs < 2; ++qs) {
                    cfr[qs][mt] = MFMA16K(vv.q[0], pk[qs][2 * kc8 + 0].s, cfr[qs][mt]);
                    cfr[qs][mt] = MFMA16K(vv.q[1], pk[qs][2 * kc8 + 1].s, cfr[qs][mt]);
                }
            }
        }
        __builtin_amdgcn_s_setprio(0);
    };

    // pipeline: stage issued right after barrier (full phase of flight),
    // drained by vmcnt(0) just before the next barrier. Ring-2 is safe:
    // stage(h+1) is issued only after all waves passed barrier(h), i.e.
    // after every wave finished reading slot (h-1)&1 == (h+1)&1.
    stage(0, 0);
    for (int h = 0; h < 8; ++h) {
        asm volatile("s_waitcnt vmcnt(0)" ::: "memory");
        __builtin_amdgcn_s_barrier();
        asm volatile("" ::: "memory");
        if (h < 7) stage(h + 1, (h + 1) & 1);
        tile_step(h & 1);
    }

    // all waves done with slots before reuse as transpose scratch
    __builtin_amdgcn_s_barrier();
    asm volatile("" ::: "memory");

    // epilogue: transpose ctx (32 rows/wave) through per-wave LDS region so
    // partial ctx goes out as coalesced bf16 16B stores.
    {
        __bf16* tb = (__bf16*)sbuf + w * 2176;     // 32 rows x stride 68
        #pragma unroll
        for (int qs = 0; qs < 2; ++qs)
            #pragma unroll
            for (int mt = 0; mt < 4; ++mt) {
                bf16x4 v;
                #pragma unroll
                for (int r = 0; r < 4; ++r) v[r] = (__bf16)cfr[qs][mt][r];
                *(bf16x4*)&tb[(qs * 16 + l15) * 68 + mt * 16 + quad * 4] = v;
            }
        const int rowbase = (split * 4 + b) * 4096 + l0 + w * 32;
        #pragma unroll
        for (int hh = 0; hh < 4; ++hh) {
            const int chunk = lane + hh * 64;      // 0..255
            const int tok = chunk >> 3, c8 = chunk & 7;
            bf16x8 v = *(const bf16x8*)&tb[tok * 68 + c8 * 8];
            *(bf16x8*)(Ops + (size_t)(rowbase + tok) * 64 + c8 * 8) = v;
        }
        #pragma unroll
        for (int qs = 0; qs < 2; ++qs) {
            float lr = l_acc[qs];
            lr += __shfl_xor(lr, 16);
            lr += __shfl_xor(lr, 32);
            if (quad == 0) Lws[rowbase + qs * 16 + l15] = lr;
        }
    }
}

// ---------------------------------------------------------------------------
// Kernel 3: split-combine (pure sum, bf16 partials) + output projection
// (bf16 MFMA) + bias + residual. grid = 1024 (b x 256 x 16 tok).
// ---------------------------------------------------------------------------
__global__ __launch_bounds__(256) void outproj_kernel(
    const float* __restrict__ inpt,
    const __bf16* __restrict__ Ops, const float* __restrict__ Lws,
    const float* __restrict__ Wo, const float* __restrict__ bo,
    float* __restrict__ out)
{
    __shared__ __align__(16) __bf16 cx[16 * 72];    // combined ctx [tok][d]
    const int bid = blockIdx.x;
    const int b   = bid >> 8;
    const int l0  = (bid & 255) << 4;
    const int t   = threadIdx.x;

    // combine: thread (token = t>>4, d4 = (t&15)*4); partials sum directly
    {
        const int token = t >> 4, d4 = (t & 15) << 2;
        const int rowb  = b * 4096 + l0 + token;
        float denom = 0.f;
        #pragma unroll
        for (int s = 0; s < SPLIT; ++s) denom += Lws[s * 16384 + rowb];
        const float inv = 1.f / denom;
        float ax = 0.f, ay = 0.f, az = 0.f, aw = 0.f;
        #pragma unroll
        for (int s = 0; s < SPLIT; ++s) {
            const bf16x4 v = *(const bf16x4*)(Ops
                + ((size_t)(s * 16384 + rowb)) * 64 + d4);
            ax += (float)v[0]; ay += (float)v[1];
            az += (float)v[2]; aw += (float)v[3];
        }
        bf16x4 pv;
        pv[0] = (__bf16)(ax * inv); pv[1] = (__bf16)(ay * inv);
        pv[2] = (__bf16)(az * inv); pv[3] = (__bf16)(aw * inv);
        *(bf16x4*)&cx[token * 72 + d4] = pv;
    }
    __syncthreads();

    const int w    = t >> 6;
    const int lane = t & 63;
    const int quad = lane >> 4;
    const int l15  = lane & 15;

    f32x4 acc[2];
    #pragma unroll
    for (int mi = 0; mi < 2; ++mi)
        #pragma unroll
        for (int r = 0; r < 4; ++r) acc[mi][r] = 0.f;

    #pragma unroll
    for (int ks = 0; ks < 2; ++ks) {
        bf16x8 bfrag = *(const bf16x8*)&cx[l15 * 72 + ks * 32 + quad * 8];  // B[n=tok][k=d]
        #pragma unroll
        for (int mi = 0; mi < 2; ++mi) {
            const int crow = (w * 2 + mi) * 16 + l15;
            const float* Wp = Wo + crow * 64 + ks * 32 + quad * 8;
            float4 wa = *(const float4*)Wp;
            float4 wb = *(const float4*)(Wp + 4);
            bf16x8 afrag;
            afrag[0] = (__bf16)wa.x; afrag[1] = (__bf16)wa.y;
            afrag[2] = (__bf16)wa.z; afrag[3] = (__bf16)wa.w;
            afrag[4] = (__bf16)wb.x; afrag[5] = (__bf16)wb.y;
            afrag[6] = (__bf16)wb.z; afrag[7] = (__bf16)wb.w;
            acc[mi] = MFMA32(afrag, bfrag, acc[mi]);     // D[m=c][n=tok]
        }
    }

    // epilogue: rows (quad*4+r) = c offset, col l15 = token
    #pragma unroll
    for (int mi = 0; mi < 2; ++mi) {
        #pragma unroll
        for (int r = 0; r < 4; ++r) {
            const int c = (w * 2 + mi) * 16 + quad * 4 + r;
            const size_t addr = ((size_t)(b * 128 + c)) * 4096 + l0 + l15;
            out[addr] = inpt[addr] + bo[c] + acc[mi][r];
        }
    }
}

// ---------------------------------------------------------------------------
extern "C" void kernel_launch(void* const* d_in, const int* in_sizes, int n_in,
                              void* d_out, int out_size, void* d_ws, size_t ws_size,
                              hipStream_t stream)
{
    const float* inpt = (const float*)d_in[0];
    const float* Wq   = (const float*)d_in[1];
    const float* bq   = (const float*)d_in[2];
    const float* Wk   = (const float*)d_in[3];
    const float* bk   = (const float*)d_in[4];
    const float* Wv   = (const float*)d_in[5];
    const float* bv   = (const float*)d_in[6];
    const float* Wo   = (const float*)d_in[7];
    const float* bo   = (const float*)d_in[8];
    float* out = (float*)d_out;

    char* ws = (char*)d_ws;
    const size_t MB = (size_t)1 << 20;
    __bf16* Qws  = (__bf16*)(ws + 0 * MB);
    __bf16* Kws  = (__bf16*)(ws + 2 * MB);         // MFMA-permuted tile layout
    __bf16* VTws = (__bf16*)(ws + 4 * MB);         // permuted tile layout
    __bf16* Ops  = (__bf16*)(ws + 6 * MB);         // SPLIT(8) x 2.1MB = 16.8 MB
    float*  Lws  = (float*)(ws + 24 * MB);         // 512 KB

    qkv_kernel<<<1024, 256, 0, stream>>>(inpt, Wq, bq, Wk, bk, Wv, bv, Qws, Kws, VTws);
    attn_kernel<<<SPLIT * 128, 256, 0, stream>>>(Qws, Kws, VTws, Ops, Lws);
    outproj_kernel<<<1024, 256, 0, stream>>>(inpt, Ops, Lws, Wo, bo, out);
}

// Round 4
// 118.520 us; speedup vs baseline: 1.4526x; 1.0545x over previous
//
#include <hip/hip_runtime.h>
#include <hip/hip_bf16.h>

typedef __bf16 bf16x8 __attribute__((ext_vector_type(8)));
typedef __bf16 bf16x4 __attribute__((ext_vector_type(4)));
typedef short  s16x4  __attribute__((ext_vector_type(4)));
typedef float  f32x4  __attribute__((ext_vector_type(4)));

#define MFMA32(a, b, c) __builtin_amdgcn_mfma_f32_16x16x32_bf16((a), (b), (c), 0, 0, 0)
#define MFMA16K(a, b, c) __builtin_amdgcn_mfma_f32_16x16x16bf16_1k((a), (b), (c), 0, 0, 0)

#if __has_builtin(__builtin_amdgcn_exp2f)
#define EXP2F(x) __builtin_amdgcn_exp2f(x)
#else
#define EXP2F(x) __expf(0.6931471805599453f * (x))
#endif

// async global->LDS, 16B per lane. LDS dest must be wave-uniform base.
#define GL16(G, L)                                                            \
    __builtin_amdgcn_global_load_lds(                                         \
        (const __attribute__((address_space(1))) void*)(G),                   \
        (__attribute__((address_space(3))) void*)(L), 16, 0, 0)

#define SPLIT 8
// BS=4, C=128, L=4096, D=64. Q pre-scaled by 0.125*log2(e): softmax in base 2.
// Fixed-bound softmax: p = 2^(s - BBOUND); the 2^(m-B) factor cancels in the
// final normalization. BBOUND folded into QK MFMA accumulator init.
#define QSCALE 0.18033688011112042f
#define BBOUND 12.0f

// K workspace layout (MFMA-permuted, per 64-key tile contiguous 8 KB):
//   Kp[b][kt][nt][half][quad][l15][i]  (key = nt*16+l15, d = half*32+quad*8+i)
// V workspace layout (permuted, per 64-key tile contiguous 8 KB):
//   Vp[b][kt][d][quad][kc][i]  (quad=key>>2&3, kc=key>>4, i=key&3)
// Wqkv_b: [msel][64][128] bf16 row-major (linear cast of Wq|Wk|Wv)
// Wo_b:   [128][64] bf16 row-major (linear cast of Wo)

// ---------------------------------------------------------------------------
// Kernel 0: one-time weight cast f32 -> bf16 (linear copy). 32768 elements.
// ---------------------------------------------------------------------------
__global__ __launch_bounds__(256) void wprep_kernel(
    const float* __restrict__ Wq, const float* __restrict__ Wk,
    const float* __restrict__ Wv, const float* __restrict__ Wo,
    __bf16* __restrict__ Wqkv_b, __bf16* __restrict__ Wo_b)
{
    const int idx = (blockIdx.x * 256 + threadIdx.x) * 4;   // 32 blocks
    const float* src;
    __bf16* dst;
    if (idx < 8192)       { src = Wq + idx;         dst = Wqkv_b + idx; }
    else if (idx < 16384) { src = Wk + idx - 8192;  dst = Wqkv_b + idx; }
    else if (idx < 24576) { src = Wv + idx - 16384; dst = Wqkv_b + idx; }
    else                  { src = Wo + idx - 24576; dst = Wo_b + idx - 24576; }
    float4 v = *(const float4*)src;
    bf16x4 o;
    o[0] = (__bf16)v.x; o[1] = (__bf16)v.y;
    o[2] = (__bf16)v.z; o[3] = (__bf16)v.w;
    *(bf16x4*)dst = o;
}

// ---------------------------------------------------------------------------
// Kernel 1: QKV projection, bf16 MFMA. grid = 256 (b x 64 tiles of 64 tok).
// Each wave owns 16 tokens (m-subtile) x all 12 n-tiles; weights read as
// pre-cast bf16 b128 fragments (no per-block f32 conversion, L1-shared).
// Per-fragment offset in Wqkv_b is simply j*2048 + l15*128 + ks*32 + quad*8.
// ---------------------------------------------------------------------------
__global__ __launch_bounds__(256, 4) void qkv_kernel(
    const float* __restrict__ inpt,
    const float* __restrict__ bq, const float* __restrict__ bk,
    const float* __restrict__ bv,
    const __bf16* __restrict__ Wqkv_b,
    __bf16* __restrict__ Qws, __bf16* __restrict__ Kws, __bf16* __restrict__ VTws)
{
    __shared__ __align__(16) __bf16 xT[64 * 136];   // [tok][c]
    __shared__ __align__(16) __bf16 os[64 * 136];   // [tok][qk-out 0..127]
    const int bid = blockIdx.x;
    const int b   = bid >> 6;
    const int l0  = (bid & 63) << 6;                // 64 tokens
    const int t   = threadIdx.x;

    // stage x^T: thread (c = t>>1, half = t&1) loads 32 floats of row c
    {
        const int c = t >> 1, half = t & 1;
        const float* xin = inpt + ((size_t)(b * 128 + c)) * 4096 + l0 + half * 32;
        #pragma unroll
        for (int i = 0; i < 8; ++i) {
            float4 v = *(const float4*)(xin + i * 4);
            const int tok = half * 32 + i * 4;
            xT[(tok + 0) * 136 + c] = (__bf16)v.x;
            xT[(tok + 1) * 136 + c] = (__bf16)v.y;
            xT[(tok + 2) * 136 + c] = (__bf16)v.z;
            xT[(tok + 3) * 136 + c] = (__bf16)v.w;
        }
    }
    __syncthreads();

    const int w    = t >> 6;
    const int lane = t & 63;
    const int quad = lane >> 4;
    const int l15  = lane & 15;

    f32x4 acc[12];
    #pragma unroll
    for (int j = 0; j < 12; ++j)
        #pragma unroll
        for (int r = 0; r < 4; ++r) acc[j][r] = 0.f;

    #pragma unroll
    for (int ks = 0; ks < 4; ++ks) {
        bf16x8 af = *(const bf16x8*)&xT[(w * 16 + l15) * 136 + ks * 32 + quad * 8];
        #pragma unroll
        for (int j = 0; j < 12; ++j) {
            bf16x8 bf = *(const bf16x8*)(Wqkv_b + j * 2048 + l15 * 128
                                         + ks * 32 + quad * 8);
            acc[j] = MFMA32(af, bf, acc[j]);        // D[m=tok][n=out]
        }
    }

    // epilogue: D rows (quad*4+r) = token (within wave's 16), col l15 = out
    #pragma unroll
    for (int j = 0; j < 12; ++j) {
        const int msel = j >> 2;
        const int o0   = (j & 3) * 16;
        const float* bb = (msel == 0) ? bq : ((msel == 1) ? bk : bv);
        float bias = bb[o0 + l15];
        if (msel < 2) {
            const float scl = (msel == 0) ? QSCALE : 1.0f;
            const int oc = j * 16 + l15;            // 0..127
            #pragma unroll
            for (int r = 0; r < 4; ++r)
                os[(w * 16 + quad * 4 + r) * 136 + oc]
                    = (__bf16)((acc[j][r] + bias) * scl);
        } else {
            // permuted V store: key = w*16 + quad*4 + r within the block's
            // single 64-key tile -> kc = w, quad_v = quad, i = r.
            const int d  = o0 + l15;
            const int kt = bid & 63;
            bf16x4 v;
            #pragma unroll
            for (int r = 0; r < 4; ++r) v[r] = (__bf16)(acc[j][r] + bias);
            *(bf16x4*)(VTws + (size_t)b * 262144 + kt * 4096
                       + d * 64 + quad * 16 + w * 4) = v;
        }
    }
    __syncthreads();

    // Q store coalesced [l][64]; K store to the MFMA-permuted tile layout.
    // 1024 16B-chunks: chunk cid -> tok = cid>>4, c8 = cid&15 (c8<8 -> Q).
    #pragma unroll
    for (int g = 0; g < 4; ++g) {
        const int cid = t + g * 256;
        const int tok = cid >> 4, c8 = cid & 15;
        bf16x8 v = *(const bf16x8*)&os[tok * 136 + c8 * 8];
        if (c8 < 8) {
            *(bf16x8*)(Qws + ((size_t)(b * 4096 + l0 + tok)) * 64 + c8 * 8) = v;
        } else {
            const int d8 = c8 - 8;                  // d = d8*8 .. +7
            __bf16* dst = Kws + (size_t)b * 262144
                + (bid & 63) * 4096           // tile
                + (tok >> 4) * 1024           // nt subtile
                + (d8 >> 2) * 512             // half = d>>5
                + (d8 & 3) * 128              // quad = (d>>3)&3
                + (tok & 15) * 8;             // l15 = key&15
            *(bf16x8*)dst = v;
        }
    }
}

// ---------------------------------------------------------------------------
// Kernel 2: flash attention, split-K, fixed-bound softmax (no online max).
// (byte-identical to round 3: 32 q-rows/wave, K+V staged via global_load_lds
// into ring-2 LDS, vmcnt(0)+s_barrier pipeline, setprio around PV MFMAs.)
// grid = SPLIT x 128; block = 128 q (wave owns 32), 8 k-tiles of 64 keys.
// ---------------------------------------------------------------------------
__global__ __launch_bounds__(256, 4) void attn_kernel(
    const __bf16* __restrict__ Qws, const __bf16* __restrict__ Kws,
    const __bf16* __restrict__ VTws,
    __bf16* __restrict__ Ops, float* __restrict__ Lws)
{
    // [slot][0..4096) = K tile, [slot][4096..8192) = V tile
    __shared__ __align__(16) __bf16 sbuf[2][8192];

    const int bid   = blockIdx.x;
    const int split = bid >> 7;
    const int qi    = bid & 127;
    const int b  = qi >> 5;
    const int l0 = (qi & 31) << 7;     // 128 q-rows per block
    const int t    = threadIdx.x;
    const int w    = t >> 6;
    const int lane = t & 63;
    const int quad = lane >> 4;
    const int l15  = lane & 15;

    // Q fragments for 2 subtiles (rows w*32 + qs*16 + l15), pre-scaled
    bf16x8 qf[2][2];
    #pragma unroll
    for (int qs = 0; qs < 2; ++qs) {
        const __bf16* qptr = Qws
            + ((size_t)(b * 4096 + l0 + w * 32 + qs * 16 + l15)) * 64 + quad * 8;
        qf[qs][0] = *(const bf16x8*)qptr;
        qf[qs][1] = *(const bf16x8*)(qptr + 32);
    }

    f32x4 cfr[2][4];
    #pragma unroll
    for (int qs = 0; qs < 2; ++qs)
        #pragma unroll
        for (int mt = 0; mt < 4; ++mt)
            #pragma unroll
            for (int r = 0; r < 4; ++r) cfr[qs][mt][r] = 0.f;
    float l_acc[2] = {0.f, 0.f};

    // hoisted V LDS element offsets (within V half of slot)
    int voff[8];
    #pragma unroll
    for (int mt = 0; mt < 4; ++mt) {
        const int d = mt * 16 + l15;
        #pragma unroll
        for (int kc8 = 0; kc8 < 2; ++kc8)
            voff[kc8 * 4 + mt] = d * 64 + (((2 * quad + kc8) ^ (d & 7)) * 8);
    }

    // staging source pointers (per-thread); LDS dests wave-uniform
    const uint4* Vg = (const uint4*)(VTws + ((size_t)b << 18));
    const int rw = t >> 3, cw = (t & 7) ^ ((t >> 3) & 7);
    const uint4* vbase = Vg + rw * 8 + cw + split * 4096;   // swizzled source
    const uint4* kbase = (const uint4*)(Kws + ((size_t)b << 18))
                       + t + split * 4096;                  // linear source

    union B4 { bf16x4 h; s16x4 s; };
    union V8 { bf16x8 v; s16x4 q[2]; };

    auto stage = [&](int kt, int slot) {                    // 4 GL16 / thread
        __bf16* Kd = &sbuf[slot][0];
        __bf16* Vd = &sbuf[slot][4096];
        const uint4* kp = kbase + kt * 512;
        const uint4* vp = vbase + kt * 512;
        GL16(kp,       Kd +        w * 512);
        GL16(kp + 256, Kd + 2048 + w * 512);
        GL16(vp,       Vd +        w * 512);
        GL16(vp + 256, Vd + 2048 + w * 512);
    };

    auto tile_step = [&](int slot) {
        const __bf16* Kb = &sbuf[slot][0];
        const __bf16* Vb = &sbuf[slot][4096];
        // ---- QK^T: K frags from LDS, shared across both q-subtiles -------
        B4 pk[2][4];
        #pragma unroll
        for (int nt = 0; nt < 4; ++nt) {
            bf16x8 k0 = *(const bf16x8*)(Kb + nt * 1024 +       lane * 8);
            bf16x8 k1 = *(const bf16x8*)(Kb + nt * 1024 + 512 + lane * 8);
            #pragma unroll
            for (int qs = 0; qs < 2; ++qs) {
                f32x4 a = {-BBOUND, -BBOUND, -BBOUND, -BBOUND};
                a = MFMA32(k0, qf[qs][0], a);
                a = MFMA32(k1, qf[qs][1], a);
                float p0 = EXP2F(a[0]), p1 = EXP2F(a[1]);
                float p2 = EXP2F(a[2]), p3 = EXP2F(a[3]);
                pk[qs][nt].h[0] = (__bf16)p0; pk[qs][nt].h[1] = (__bf16)p1;
                pk[qs][nt].h[2] = (__bf16)p2; pk[qs][nt].h[3] = (__bf16)p3;
                l_acc[qs] += (p0 + p1) + (p2 + p3);   // lane-local; reduce at end
            }
        }
        // ---- PV: each V b128 feeds 4 MFMAs (2 per q-subtile) --------------
        __builtin_amdgcn_s_setprio(1);
        #pragma unroll
        for (int kc8 = 0; kc8 < 2; ++kc8) {
            #pragma unroll
            for (int mt = 0; mt < 4; ++mt) {
                V8 vv;
                vv.v = *(const bf16x8*)&Vb[voff[kc8 * 4 + mt]];
                #pragma unroll
                for (int qs = 0; qs < 2; ++qs) {
                    cfr[qs][mt] = MFMA16K(vv.q[0], pk[qs][2 * kc8 + 0].s, cfr[qs][mt]);
                    cfr[qs][mt] = MFMA16K(vv.q[1], pk[qs][2 * kc8 + 1].s, cfr[qs][mt]);
                }
            }
        }
        __builtin_amdgcn_s_setprio(0);
    };

    // pipeline: stage issued right after barrier (full phase of flight),
    // drained by vmcnt(0) just before the next barrier.
    stage(0, 0);
    for (int h = 0; h < 8; ++h) {
        asm volatile("s_waitcnt vmcnt(0)" ::: "memory");
        __builtin_amdgcn_s_barrier();
        asm volatile("" ::: "memory");
        if (h < 7) stage(h + 1, (h + 1) & 1);
        tile_step(h & 1);
    }

    // all waves done with slots before reuse as transpose scratch
    __builtin_amdgcn_s_barrier();
    asm volatile("" ::: "memory");

    // epilogue: transpose ctx (32 rows/wave) through per-wave LDS region so
    // partial ctx goes out as coalesced bf16 16B stores.
    {
        __bf16* tb = (__bf16*)sbuf + w * 2176;     // 32 rows x stride 68
        #pragma unroll
        for (int qs = 0; qs < 2; ++qs)
            #pragma unroll
            for (int mt = 0; mt < 4; ++mt) {
                bf16x4 v;
                #pragma unroll
                for (int r = 0; r < 4; ++r) v[r] = (__bf16)cfr[qs][mt][r];
                *(bf16x4*)&tb[(qs * 16 + l15) * 68 + mt * 16 + quad * 4] = v;
            }
        const int rowbase = (split * 4 + b) * 4096 + l0 + w * 32;
        #pragma unroll
        for (int hh = 0; hh < 4; ++hh) {
            const int chunk = lane + hh * 64;      // 0..255
            const int tok = chunk >> 3, c8 = chunk & 7;
            bf16x8 v = *(const bf16x8*)&tb[tok * 68 + c8 * 8];
            *(bf16x8*)(Ops + (size_t)(rowbase + tok) * 64 + c8 * 8) = v;
        }
        #pragma unroll
        for (int qs = 0; qs < 2; ++qs) {
            float lr = l_acc[qs];
            lr += __shfl_xor(lr, 16);
            lr += __shfl_xor(lr, 32);
            if (quad == 0) Lws[rowbase + qs * 16 + l15] = lr;
        }
    }
}

// ---------------------------------------------------------------------------
// Kernel 3: split-combine + output projection + bias + residual.
// grid = 256 (b x 64 tiles of 64 tok). Wo from pre-cast bf16; each weight
// A-fragment reused across 4 token-subtiles.
// ---------------------------------------------------------------------------
__global__ __launch_bounds__(256, 4) void outproj_kernel(
    const float* __restrict__ inpt,
    const __bf16* __restrict__ Ops, const float* __restrict__ Lws,
    const __bf16* __restrict__ Wo_b, const float* __restrict__ bo,
    float* __restrict__ out)
{
    __shared__ __align__(16) __bf16 cx[64 * 72];    // combined ctx [tok][d]
    const int bid = blockIdx.x;
    const int b   = bid >> 6;
    const int l0  = (bid & 63) << 6;
    const int t   = threadIdx.x;

    // combine: thread owns token = t>>2, four d16-groups (t&3)+4g.
    {
        const int token = t >> 2;
        const int rowb  = b * 4096 + l0 + token;
        float denom = 0.f;
        #pragma unroll
        for (int s = 0; s < SPLIT; ++s) denom += Lws[s * 16384 + rowb];
        const float inv = 1.f / denom;
        #pragma unroll
        for (int g = 0; g < 4; ++g) {
            const int d4 = (((t & 3) + g * 4)) << 2;
            float ax = 0.f, ay = 0.f, az = 0.f, aw = 0.f;
            #pragma unroll
            for (int s = 0; s < SPLIT; ++s) {
                const bf16x4 v = *(const bf16x4*)(Ops
                    + ((size_t)(s * 16384 + rowb)) * 64 + d4);
                ax += (float)v[0]; ay += (float)v[1];
                az += (float)v[2]; aw += (float)v[3];
            }
            bf16x4 pv;
            pv[0] = (__bf16)(ax * inv); pv[1] = (__bf16)(ay * inv);
            pv[2] = (__bf16)(az * inv); pv[3] = (__bf16)(aw * inv);
            *(bf16x4*)&cx[token * 72 + d4] = pv;
        }
    }
    __syncthreads();

    const int w    = t >> 6;
    const int lane = t & 63;
    const int quad = lane >> 4;
    const int l15  = lane & 15;

    f32x4 acc[2][4];
    #pragma unroll
    for (int mi = 0; mi < 2; ++mi)
        #pragma unroll
        for (int nt = 0; nt < 4; ++nt)
            #pragma unroll
            for (int r = 0; r < 4; ++r) acc[mi][nt][r] = 0.f;

    #pragma unroll
    for (int ks = 0; ks < 2; ++ks) {
        bf16x8 bfr[4];
        #pragma unroll
        for (int nt = 0; nt < 4; ++nt)
            bfr[nt] = *(const bf16x8*)&cx[(nt * 16 + l15) * 72 + ks * 32 + quad * 8];
        #pragma unroll
        for (int mi = 0; mi < 2; ++mi) {
            const int crow = (w * 2 + mi) * 16 + l15;
            bf16x8 af = *(const bf16x8*)(Wo_b + crow * 64 + ks * 32 + quad * 8);
            #pragma unroll
            for (int nt = 0; nt < 4; ++nt)
                acc[mi][nt] = MFMA32(af, bfr[nt], acc[mi][nt]);  // D[m=c][n=tok]
        }
    }

    // epilogue: rows (quad*4+r) = c offset, col l15 = token within subtile
    #pragma unroll
    for (int mi = 0; mi < 2; ++mi) {
        const int c0 = (w * 2 + mi) * 16 + quad * 4;
        #pragma unroll
        for (int nt = 0; nt < 4; ++nt) {
            #pragma unroll
            for (int r = 0; r < 4; ++r) {
                const int c = c0 + r;
                const size_t addr = ((size_t)(b * 128 + c)) * 4096
                                  + l0 + nt * 16 + l15;
                out[addr] = inpt[addr] + bo[c] + acc[mi][nt][r];
            }
        }
    }
}

// ---------------------------------------------------------------------------
extern "C" void kernel_launch(void* const* d_in, const int* in_sizes, int n_in,
                              void* d_out, int out_size, void* d_ws, size_t ws_size,
                              hipStream_t stream)
{
    const float* inpt = (const float*)d_in[0];
    const float* Wq   = (const float*)d_in[1];
    const float* bq   = (const float*)d_in[2];
    const float* Wk   = (const float*)d_in[3];
    const float* bk   = (const float*)d_in[4];
    const float* Wv   = (const float*)d_in[5];
    const float* bv   = (const float*)d_in[6];
    const float* Wo   = (const float*)d_in[7];
    const float* bo   = (const float*)d_in[8];
    float* out = (float*)d_out;

    char* ws = (char*)d_ws;
    const size_t MB = (size_t)1 << 20;
    __bf16* Qws    = (__bf16*)(ws + 0 * MB);
    __bf16* Kws    = (__bf16*)(ws + 2 * MB);       // MFMA-permuted tile layout
    __bf16* VTws   = (__bf16*)(ws + 4 * MB);       // permuted tile layout
    __bf16* Ops    = (__bf16*)(ws + 6 * MB);       // SPLIT(8) x 2.1MB
    float*  Lws    = (float*)(ws + 24 * MB);       // 512 KB
    __bf16* Wqkv_b = (__bf16*)(ws + 25 * MB);      // 48 KB
    __bf16* Wo_b   = (__bf16*)(ws + 25 * MB + (64 << 10));  // 16 KB

    wprep_kernel<<<32, 256, 0, stream>>>(Wq, Wk, Wv, Wo, Wqkv_b, Wo_b);
    qkv_kernel<<<256, 256, 0, stream>>>(inpt, bq, bk, bv, Wqkv_b, Qws, Kws, VTws);
    attn_kernel<<<SPLIT * 128, 256, 0, stream>>>(Qws, Kws, VTws, Ops, Lws);
    outproj_kernel<<<256, 256, 0, stream>>>(inpt, Ops, Lws, Wo_b, bo, out);
}